// Round 10
// baseline (1266.304 us; speedup 1.0000x reference)
//
#include <hip/hip_runtime.h>

#define HW   4096
#define DIM  256
#define NB   8

typedef short bf16x8 __attribute__((ext_vector_type(8)));
typedef short s16x4  __attribute__((ext_vector_type(4)));
typedef float f32x4  __attribute__((ext_vector_type(4)));
typedef float f32x16 __attribute__((ext_vector_type(16)));
typedef unsigned int u32_g __attribute__((address_space(1)));
typedef unsigned int u32_l __attribute__((address_space(3)));

// round-to-nearest-even split of fp32 into bf16 hi + bf16 lo
__device__ __forceinline__ void split_bf16(float x, short& hi, short& lo) {
    unsigned u  = __builtin_bit_cast(unsigned, x);
    unsigned rh = (u + 0x7FFFu + ((u >> 16) & 1u)) >> 16;
    hi = (short)rh;
    float hf  = __builtin_bit_cast(float, rh << 16);
    float rem = x - hf;
    unsigned u2 = __builtin_bit_cast(unsigned, rem);
    unsigned rl = (u2 + 0x7FFFu + ((u2 >> 16) & 1u)) >> 16;
    lo = (short)rl;
}

__device__ __forceinline__ f32x4 mfma16(bf16x8 a, bf16x8 b, f32x4 c) {
    return __builtin_amdgcn_mfma_f32_16x16x32_bf16(a, b, c, 0, 0, 0);
}
__device__ __forceinline__ f32x16 mfma32(bf16x8 a, bf16x8 b, f32x16 c) {
    return __builtin_amdgcn_mfma_f32_32x32x16_bf16(a, b, c, 0, 0, 0);
}

__device__ __forceinline__ void gload16(const void* g, void* l) {
    __builtin_amdgcn_global_load_lds((const u32_g*)g, (u32_l*)l, 16, 0, 0);
}
__device__ __forceinline__ void gload4(const void* g, void* l) {
    __builtin_amdgcn_global_load_lds((const u32_g*)g, (u32_l*)l, 4, 0, 0);
}

// ===========================================================================
// pass0_T: X[b][256][4096] f32 -> XT_hi/lo[b][4096][256] bf16-shorts,
// each 512-B output row byte-swizzled: colbyte ^= ((row&15)<<4)
// ===========================================================================
extern "C" __global__ void __launch_bounds__(256)
pass0_T(const float* __restrict__ src, short* __restrict__ dsth,
        short* __restrict__ dstl)
{
    __shared__ __attribute__((aligned(16))) short TH[16][264];
    __shared__ __attribute__((aligned(16))) short TL[16][264];
    const int b   = blockIdx.y;
    const int hw0 = blockIdx.x * 16;
    const int t   = threadIdx.x;
    const float* sb = src + (size_t)b * DIM * HW;

    {
        const int rl = t & 15;     // hw within tile
        const int dl = t >> 4;     // d base
        #pragma unroll
        for (int dp = 0; dp < 16; ++dp) {
            int d = dl + dp * 16;
            float x = sb[(size_t)d * HW + hw0 + rl];
            short h, l; split_bf16(x, h, l);
            TH[rl][d] = h; TL[rl][d] = l;
        }
    }
    __syncthreads();

    const int r   = t >> 4;          // row (hw) in tile, 0..15
    const int c0  = (t & 15) * 2;    // first 16-B chunk of 2
    const int swz = r << 4;          // (hw0+r)&15 == r
    size_t rowbyte = ((size_t)b * HW + hw0 + r) * (size_t)(DIM * 2);
    char* dh = (char*)dsth + rowbyte;
    char* dl = (char*)dstl + rowbyte;
    #pragma unroll
    for (int j = 0; j < 2; ++j) {
        int cb  = (c0 + j) * 16;
        int cbs = cb ^ swz;
        *(f32x4*)(dh + cbs) = *(const f32x4*)((const char*)&TH[r][0] + cb);
        *(f32x4*)(dl + cbs) = *(const f32x4*)((const char*)&TL[r][0] + cb);
    }
}

// pass0_V: V[b][256][4096] f32 -> V2[b][512 segs][256 v][8 hi + 8 lo] shorts
extern "C" __global__ void __launch_bounds__(256)
pass0_V(const float* __restrict__ V, short* __restrict__ v2)
{
    const int b = blockIdx.y, v = blockIdx.x, t = threadIdx.x;
    const float* sv = V + ((size_t)b * DIM + v) * HW + t * 16;
    #pragma unroll
    for (int s = 0; s < 2; ++s) {
        f32x4 x0 = *(const f32x4*)(sv + s * 8);
        f32x4 x1 = *(const f32x4*)(sv + s * 8 + 4);
        s16x4 h0, l0, h1, l1;
        #pragma unroll
        for (int j = 0; j < 4; ++j) {
            short h, l;
            split_bf16(x0[j], h, l); h0[j] = h; l0[j] = l;
            split_bf16(x1[j], h, l); h1[j] = h; l1[j] = l;
        }
        short* dp = v2 + (((size_t)b * 512 + (size_t)(t * 2 + s)) * DIM + v) * 16;
        *(s16x4*)(dp + 0)  = h0;
        *(s16x4*)(dp + 4)  = h1;
        *(s16x4*)(dp + 8)  = l0;
        *(s16x4*)(dp + 12) = l1;
    }
}

// ===========================================================================
// k9_stats (unchanged): per-k-column online max / exp-sum over all q.
// ===========================================================================
extern "C" __global__ void __launch_bounds__(512, 2)
k9_stats(const short* __restrict__ KTh, const short* __restrict__ KTl,
         const short* __restrict__ QTh, const short* __restrict__ QTl,
         float* __restrict__ m_out, float* __restrict__ il_out)
{
    __shared__ __attribute__((aligned(16))) short QH[2][64][256];  // 64 KB
    __shared__ __attribute__((aligned(16))) short QL[2][64][256];  // 64 KB
    __shared__ __attribute__((aligned(16))) float MRG[2][128][2];  // 2 KB

    const int id   = blockIdx.x;
    const int b    = id & 7;
    const int k0b  = (id >> 3) * 128;
    const int t    = threadIdx.x;
    const int lane = t & 63;
    const int w    = t >> 6;
    const int l32  = lane & 31;
    const int g2   = lane >> 5;
    const int wk   = w >> 1;        // k quarter (32 rows)
    const int wq   = w & 1;         // q half (32 cols)

    bf16x8 kh[16], kl[16];
    {
        const int krow = k0b + wk * 32 + l32;
        const char* rh = (const char*)KTh + ((size_t)b * HW + krow) * 512;
        const char* rl = (const char*)KTl + ((size_t)b * HW + krow) * 512;
        const int swz = (l32 & 15) << 4;
        #pragma unroll
        for (int s = 0; s < 16; ++s) {
            int cb = (s * 32 + g2 * 16) ^ swz;
            kh[s] = *(const bf16x8*)(rh + cb);
            kl[s] = *(const bf16x8*)(rl + cb);
        }
    }

    const char* qhbase = (const char*)QTh + (size_t)b * HW * 512;
    const char* qlbase = (const char*)QTl + (size_t)b * HW * 512;
    auto stage = [&](int bi, int q0s) {
        #pragma unroll
        for (int j = 0; j < 4; ++j) {
            int cc = (j << 3) + w;             // 0..31 chunks of 1 KB
            int o  = cc * 1024;
            gload16(qhbase + (size_t)q0s * 512 + o + lane * 16,
                    (char*)&QH[bi][0][0] + o);
            gload16(qlbase + (size_t)q0s * 512 + o + lane * 16,
                    (char*)&QL[bi][0][0] + o);
        }
    };

    const int qrow = wq * 32 + l32;
    const int qswz = (l32 & 15) << 4;   // qrow&15 == l32&15

    float mr[16], lr[16];
    #pragma unroll
    for (int r = 0; r < 16; ++r) { mr[r] = -3.0e38f; lr[r] = 0.0f; }

    stage(0, 0);
    __syncthreads();

    for (int it = 0; it < 64; ++it) {
        const int cur = it & 1;
        if (it + 1 < 64) stage(cur ^ 1, (it + 1) * 64);

        const char* bhr = (const char*)&QH[cur][qrow][0];
        const char* blr = (const char*)&QL[cur][qrow][0];
        f32x16 cS;
        #pragma unroll
        for (int e = 0; e < 16; ++e) cS[e] = 0.0f;

        __builtin_amdgcn_s_setprio(1);
        #pragma unroll
        for (int s = 0; s < 16; ++s) {
            int cb = (s * 32 + g2 * 16) ^ qswz;
            bf16x8 bh = *(const bf16x8*)(bhr + cb);
            bf16x8 bl = *(const bf16x8*)(blr + cb);
            cS = mfma32(kh[s], bh, cS);         // Kh*Qh
            cS = mfma32(kh[s], bl, cS);         // Kh*Ql
            cS = mfma32(kl[s], bh, cS);         // Kl*Qh
        }
        __builtin_amdgcn_s_setprio(0);

        #pragma unroll
        for (int r = 0; r < 16; ++r) {
            float sv = cS[r];
            float nm = fmaxf(mr[r], sv);
            lr[r] = lr[r] * __expf(mr[r] - nm) + __expf(sv - nm);
            mr[r] = nm;
        }
        __syncthreads();
    }

    #pragma unroll
    for (int r = 0; r < 16; ++r) {
        float m = mr[r], l = lr[r];
        #pragma unroll
        for (int off = 1; off < 32; off <<= 1) {
            float m2 = __shfl_xor(m, off);
            float l2 = __shfl_xor(l, off);
            float nm = fmaxf(m, m2);
            l = l * __expf(m - nm) + l2 * __expf(m2 - nm);
            m = nm;
        }
        mr[r] = m; lr[r] = l;
    }
    if (l32 == 0) {
        #pragma unroll
        for (int r = 0; r < 16; ++r) {
            int klo = wk * 32 + 4 * g2 + (r & 3) + 8 * (r >> 2);
            MRG[wq][klo][0] = mr[r];
            MRG[wq][klo][1] = lr[r];
        }
    }
    __syncthreads();
    if (t < 128) {
        float m0 = MRG[0][t][0], l0 = MRG[0][t][1];
        float m1 = MRG[1][t][0], l1 = MRG[1][t][1];
        float nm = fmaxf(m0, m1);
        float l  = l0 * __expf(m0 - nm) + l1 * __expf(m1 - nm);
        m_out[b * HW + k0b + t]  = nm;
        il_out[b * HW + k0b + t] = 1.0f / l;
    }
}

// ===========================================================================
// k10_out: producer/consumer role-split. 512 thr, BQ=64, BK=64, 64 iters.
// Waves 0-3 = producers: S^T (3-chain identical to k9_stats) + exp + P-write.
// Waves 4-7 = consumers: PV (64 v-rows each) + all K staging (DMA).
// SIMD s hosts waves s and s+4 -> producer VALU overlaps consumer MFMA.
// K-hi & K-lo double-buffered LDS (staged interval-A top by consumers);
// P single [64][68] per plane: consumers copy P(it-1) frags to regs in
// interval A, producers write P(it) in interval B. 2 barriers/iter.
// grid 512 blocks (id&7 = batch, id>>3 = 64-q tile), 1 block/CU, 2 rounds.
// ===========================================================================
extern "C" __global__ void __launch_bounds__(512, 2)
k10_out(const short* __restrict__ KTh, const short* __restrict__ KTl,
        const short* __restrict__ QTh, const short* __restrict__ QTl,
        const short* __restrict__ V2,
        const float* __restrict__ m_in, const float* __restrict__ il_in,
        float* __restrict__ out)
{
    __shared__ __attribute__((aligned(16))) short KH[2][64][256];  // 64 KB
    __shared__ __attribute__((aligned(16))) short KL[2][64][256];  // 64 KB
    __shared__ __attribute__((aligned(16))) short PH[64][68];      // 8.5 KB
    __shared__ __attribute__((aligned(16))) short PL[64][68];      // 8.5 KB
    __shared__ __attribute__((aligned(16))) float MI[2][128];      // 1 KB

    const int id   = blockIdx.x;
    const int b    = id & 7;
    const int q0   = (id >> 3) * 64;
    const int t    = threadIdx.x;
    const int lane = t & 63;
    const int w    = t >> 6;
    const int l32  = lane & 31;
    const int g2   = lane >> 5;
    const bool producer = (w < 4);
    const int a    = w & 1;         // producer: k-half
    const int c    = w >> 1;        // producer: q-half
    const int cw   = w - 4;         // consumer index 0..3
    const int wv   = cw;            // consumer: v quarter (64 rows)

    // producer Q fragments (hi+lo), one-time load from swizzled rows
    bf16x8 qh[16], ql[16];
    if (producer) {
        const int qrow = q0 + c * 32 + l32;
        const char* rh = (const char*)QTh + ((size_t)b * HW + qrow) * 512;
        const char* rl = (const char*)QTl + ((size_t)b * HW + qrow) * 512;
        const int swz = (l32 & 15) << 4;
        #pragma unroll
        for (int s = 0; s < 16; ++s) {
            int cb = (s * 32 + g2 * 16) ^ swz;
            qh[s] = *(const bf16x8*)(rh + cb);
            ql[s] = *(const bf16x8*)(rl + cb);
        }
    }

    const char* khbase = (const char*)KTh + (size_t)b * HW * 512;
    const char* klbase = (const char*)KTl + (size_t)b * HW * 512;
    const float* mB   = m_in  + b * HW;
    const float* ilB  = il_in + b * HW;

    // consumer staging: 32 KB per plane = 32 chunks of 1KB over 4 waves
    auto stageK = [&](int bi, int k0s) {
        #pragma unroll
        for (int j = 0; j < 8; ++j) {
            int cc = (j << 2) + cw;
            int o  = cc * 1024;
            gload16(khbase + (size_t)k0s * 512 + o + lane * 16,
                    (char*)&KH[bi][0][0] + o);
            gload16(klbase + (size_t)k0s * 512 + o + lane * 16,
                    (char*)&KL[bi][0][0] + o);
        }
    };
    auto stageMI = [&](int bi, int k0s) {
        if (w == 4) {
            gload4(mB  + k0s + lane, (char*)&MI[bi][0]);
            gload4(ilB + k0s + lane, (char*)&MI[bi][64]);
        }
    };

    f32x16 acc[2][2];
    #pragma unroll
    for (int i = 0; i < 2; ++i)
        #pragma unroll
        for (int j = 0; j < 2; ++j)
            #pragma unroll
            for (int e = 0; e < 16; ++e) acc[i][j][e] = 0.0f;

    if (!producer) {
        stageK(0, 0);
        stageMI(0, 0);
    }
    __syncthreads();

    const int arow = a * 32 + l32;
    const int aswz = (l32 & 15) << 4;
    const int prow = c * 32 + l32;

    // persistent across the two intervals of an iteration:
    s16x4 phr[4], plr[4];               // producer: P values (regs)
    bf16x8 pbh[4][2], pbl[4][2];        // consumer: P(it-1) fragments

    auto pvStep = [&](int pit, int kc, const bf16x8* bh2, const bf16x8* bl2) {
        const int seg = pit * 8 + kc * 2 + g2;
        #pragma unroll
        for (int mt = 0; mt < 2; ++mt) {
            int v = wv * 64 + mt * 32 + l32;
            const short* vp = V2 + (((size_t)b * 512 + seg) * DIM + v) * 16;
            bf16x8 vh = *(const bf16x8*)(vp);
            bf16x8 vl = *(const bf16x8*)(vp + 8);
            #pragma unroll
            for (int qt = 0; qt < 2; ++qt) {
                acc[mt][qt] = mfma32(vh, bh2[qt], acc[mt][qt]);
                acc[mt][qt] = mfma32(vh, bl2[qt], acc[mt][qt]);
                acc[mt][qt] = mfma32(vl, bh2[qt], acc[mt][qt]);
            }
        }
    };

    for (int it = 0; it < 64; ++it) {
        const int cur = it & 1;

        // ------------------ interval A ------------------
        if (!producer) {
            if (it + 1 < 64) {
                stageK(cur ^ 1, (it + 1) * 64);
                stageMI(cur ^ 1, (it + 1) * 64);
            }
            if (it > 0) {
                // copy ALL P(it-1) fragments to regs (frees P for interval B)
                #pragma unroll
                for (int kc = 0; kc < 4; ++kc)
                    #pragma unroll
                    for (int qt = 0; qt < 2; ++qt) {
                        int pr = qt * 32 + l32;
                        const short* p0 = &PH[pr][kc * 16 + g2 * 8];
                        const short* p1 = &PL[pr][kc * 16 + g2 * 8];
                        s16x4 a0 = *(const s16x4*)(p0);
                        s16x4 a1 = *(const s16x4*)(p0 + 4);
                        s16x4 b0 = *(const s16x4*)(p1);
                        s16x4 b1 = *(const s16x4*)(p1 + 4);
                        pbh[kc][qt] = __builtin_shufflevector(a0, a1, 0,1,2,3,4,5,6,7);
                        pbl[kc][qt] = __builtin_shufflevector(b0, b1, 0,1,2,3,4,5,6,7);
                    }
                __builtin_amdgcn_s_setprio(1);
                pvStep(it - 1, 0, pbh[0], pbl[0]);
                pvStep(it - 1, 1, pbh[1], pbl[1]);
                __builtin_amdgcn_s_setprio(0);
            }
        } else {
            // S^T: 3-chain identical to k9_stats
            const char* ahr = (const char*)&KH[cur][arow][0];
            const char* alr = (const char*)&KL[cur][arow][0];
            f32x16 cS;
            #pragma unroll
            for (int e = 0; e < 16; ++e) cS[e] = 0.0f;

            __builtin_amdgcn_s_setprio(1);
            #pragma unroll
            for (int s = 0; s < 16; ++s) {
                int cb = (s * 32 + g2 * 16) ^ aswz;
                bf16x8 ah = *(const bf16x8*)(ahr + cb);
                bf16x8 al = *(const bf16x8*)(alr + cb);
                cS = mfma32(ah, qh[s], cS);         // Kh*Qh
                cS = mfma32(ah, ql[s], cS);         // Kh*Ql
                cS = mfma32(al, qh[s], cS);         // Kl*Qh
            }
            __builtin_amdgcn_s_setprio(0);

            // exp + split -> registers (written to LDS in interval B)
            #pragma unroll
            for (int run = 0; run < 4; ++run) {
                int idx = a * 32 + 4 * g2 + 8 * run;
                f32x4 m4 = *(const f32x4*)&MI[cur][idx];
                f32x4 i4 = *(const f32x4*)&MI[cur][64 + idx];
                s16x4 ph, pl;
                #pragma unroll
                for (int e = 0; e < 4; ++e) {
                    int r = run * 4 + e;
                    float p = __expf(cS[r] - m4[e]) * i4[e];
                    short h, l; split_bf16(p, h, l);
                    ph[e] = h; pl[e] = l;
                }
                phr[run] = ph; plr[run] = pl;
            }
        }

        __syncthreads();   // bar A: consumer P(it-1)-reads done; K DMA issued

        // ------------------ interval B ------------------
        if (!producer) {
            if (it > 0) {
                __builtin_amdgcn_s_setprio(1);
                pvStep(it - 1, 2, pbh[2], pbl[2]);
                pvStep(it - 1, 3, pbh[3], pbl[3]);
                __builtin_amdgcn_s_setprio(0);
            }
        } else {
            #pragma unroll
            for (int run = 0; run < 4; ++run) {
                int idx = a * 32 + 4 * g2 + 8 * run;
                *(s16x4*)&PH[prow][idx] = phr[run];
                *(s16x4*)&PL[prow][idx] = plr[run];
            }
        }

        __syncthreads();   // bar B: P(it) visible; K(it+1)/MI DMA drained
    }

    // epilogue: consumers do PV(63) (P stable in LDS), then write out
    if (!producer) {
        #pragma unroll
        for (int kc = 0; kc < 4; ++kc)
            #pragma unroll
            for (int qt = 0; qt < 2; ++qt) {
                int pr = qt * 32 + l32;
                const short* p0 = &PH[pr][kc * 16 + g2 * 8];
                const short* p1 = &PL[pr][kc * 16 + g2 * 8];
                s16x4 a0 = *(const s16x4*)(p0);
                s16x4 a1 = *(const s16x4*)(p0 + 4);
                s16x4 b0 = *(const s16x4*)(p1);
                s16x4 b1 = *(const s16x4*)(p1 + 4);
                pbh[kc][qt] = __builtin_shufflevector(a0, a1, 0,1,2,3,4,5,6,7);
                pbl[kc][qt] = __builtin_shufflevector(b0, b1, 0,1,2,3,4,5,6,7);
            }
        #pragma unroll
        for (int kc = 0; kc < 4; ++kc) pvStep(63, kc, pbh[kc], pbl[kc]);

        float* __restrict__ ob = out + (size_t)b * DIM * HW;
        #pragma unroll
        for (int mt = 0; mt < 2; ++mt)
            #pragma unroll
            for (int qt = 0; qt < 2; ++qt)
                #pragma unroll
                for (int r = 0; r < 16; ++r) {
                    int v = wv * 64 + mt * 32 + (r & 3) + 8 * (r >> 2) + 4 * g2;
                    int q = q0 + qt * 32 + l32;
                    ob[(size_t)v * HW + q] = acc[mt][qt][r];
                }
    }
}

// ===========================================================================
// FALLBACK PATH (round-1 passing kernels, used only if ws too small)
// ===========================================================================
extern "C" __global__ void __launch_bounds__(256, 1)
k_stats(const float* __restrict__ K, const float* __restrict__ Q,
        float* __restrict__ m_out, float* __restrict__ il_out)
{
    __shared__ __attribute__((aligned(16))) short KtH[64][264];
    __shared__ __attribute__((aligned(16))) short KtL[64][264];
    __shared__ __attribute__((aligned(16))) short QtH[32][264];
    __shared__ __attribute__((aligned(16))) short QtL[32][264];

    const int b = blockIdx.y, k0 = blockIdx.x * 64, t = threadIdx.x;
    const int lane = t & 63, w = t >> 6, g = lane >> 4, lq = lane & 15;
    const float* Kb = K + (size_t)b * DIM * HW;
    const float* Qb = Q + (size_t)b * DIM * HW;

    {
        const int kk = t & 63, d0 = t >> 6;
        #pragma unroll 4
        for (int pass = 0; pass < 64; ++pass) {
            int d = d0 + pass * 4;
            float x = Kb[(size_t)d * HW + k0 + kk];
            short h, l; split_bf16(x, h, l);
            KtH[kk][d] = h; KtL[kk][d] = l;
        }
    }
    float mr[4], lr[4];
    #pragma unroll
    for (int r = 0; r < 4; ++r) { mr[r] = -3.0e38f; lr[r] = 0.0f; }

    for (int q0 = 0; q0 < HW; q0 += 32) {
        __syncthreads();
        {
            const int qq = t & 31, d0 = t >> 5;
            #pragma unroll 4
            for (int pass = 0; pass < 32; ++pass) {
                int d = d0 + pass * 8;
                float x = Qb[(size_t)d * HW + q0 + qq];
                short h, l; split_bf16(x, h, l);
                QtH[qq][d] = h; QtL[qq][d] = l;
            }
        }
        __syncthreads();
        #pragma unroll
        for (int qt = 0; qt < 2; ++qt) {
            f32x4 acc = {0.f, 0.f, 0.f, 0.f};
            #pragma unroll
            for (int ds = 0; ds < 8; ++ds) {
                const int dof = ds * 32 + g * 8;
                bf16x8 ah = *(const bf16x8*)&KtH[w * 16 + lq][dof];
                bf16x8 al = *(const bf16x8*)&KtL[w * 16 + lq][dof];
                bf16x8 bh = *(const bf16x8*)&QtH[qt * 16 + lq][dof];
                bf16x8 bl = *(const bf16x8*)&QtL[qt * 16 + lq][dof];
                acc = mfma16(ah, bh, acc);
                acc = mfma16(ah, bl, acc);
                acc = mfma16(al, bh, acc);
            }
            #pragma unroll
            for (int r = 0; r < 4; ++r) {
                float s = acc[r];
                if (s > mr[r]) { lr[r] = lr[r] * __expf(mr[r] - s) + 1.0f; mr[r] = s; }
                else lr[r] += __expf(s - mr[r]);
            }
        }
    }
    #pragma unroll
    for (int r = 0; r < 4; ++r) {
        float m = mr[r], l = lr[r];
        #pragma unroll
        for (int off = 1; off < 16; off <<= 1) {
            float m2 = __shfl_xor(m, off), l2 = __shfl_xor(l, off);
            float mn = fmaxf(m, m2);
            l = l * __expf(m - mn) + l2 * __expf(m2 - mn);
            m = mn;
        }
        if (lq == 0) {
            int kg = k0 + w * 16 + g * 4 + r;
            m_out[b * HW + kg] = m;
            il_out[b * HW + kg] = 1.0f / l;
        }
    }
}

extern "C" __global__ void __launch_bounds__(256, 1)
k_attn_out(const float* __restrict__ K, const float* __restrict__ Q,
           const float* __restrict__ V,
           const float* __restrict__ m_in, const float* __restrict__ il_in,
           float* __restrict__ out)
{
    __shared__ __attribute__((aligned(16))) short QtH[64][264];
    __shared__ __attribute__((aligned(16))) short QtL[64][264];
    __shared__ __attribute__((aligned(16))) short KtH[32][264];
    __shared__ __attribute__((aligned(16))) short KtL[32][264];
    __shared__ __attribute__((aligned(16))) short PtH[64][40];
    __shared__ __attribute__((aligned(16))) short PtL[64][40];

    const int b = blockIdx.y, q0 = blockIdx.x * 64, t = threadIdx.x;
    const int lane = t & 63, w = t >> 6, g = lane >> 4, lq = lane & 15;
    const int g2 = lane >> 5, l32 = lane & 31;
    const float* Kb = K + (size_t)b * DIM * HW;
    const float* Qb = Q + (size_t)b * DIM * HW;
    const float* Vb = V + (size_t)b * DIM * HW;
    const float* mB = m_in + b * HW;
    const float* ilB = il_in + b * HW;

    {
        const int qq = t & 63, d0 = t >> 6;
        #pragma unroll 4
        for (int pass = 0; pass < 64; ++pass) {
            int d = d0 + pass * 4;
            float x = Qb[(size_t)d * HW + q0 + qq];
            short h, l; split_bf16(x, h, l);
            QtH[qq][d] = h; QtL[qq][d] = l;
        }
    }
    f32x16 acc[2][2];
    #pragma unroll
    for (int i = 0; i < 2; ++i)
        #pragma unroll
        for (int j = 0; j < 2; ++j)
            #pragma unroll
            for (int e = 0; e < 16; ++e) acc[i][j][e] = 0.0f;

    for (int k0 = 0; k0 < HW; k0 += 32) {
        __syncthreads();
        {
            const int kk = t & 31, d0 = t >> 5;
            #pragma unroll 4
            for (int pass = 0; pass < 32; ++pass) {
                int d = d0 + pass * 8;
                float x = Kb[(size_t)d * HW + k0 + kk];
                short h, l; split_bf16(x, h, l);
                KtH[kk][d] = h; KtL[kk][d] = l;
            }
        }
        __syncthreads();
        f32x4 sacc[2];
        #pragma unroll
        for (int kt = 0; kt < 2; ++kt) { f32x4 z = {0.f,0.f,0.f,0.f}; sacc[kt] = z; }
        #pragma unroll
        for (int ds = 0; ds < 8; ++ds) {
            const int dof = ds * 32 + g * 8;
            bf16x8 bh = *(const bf16x8*)&QtH[w * 16 + lq][dof];
            bf16x8 bl = *(const bf16x8*)&QtL[w * 16 + lq][dof];
            #pragma unroll
            for (int kt = 0; kt < 2; ++kt) {
                bf16x8 ah = *(const bf16x8*)&KtH[kt * 16 + lq][dof];
                bf16x8 al = *(const bf16x8*)&KtL[kt * 16 + lq][dof];
                sacc[kt] = mfma16(ah, bh, sacc[kt]);
                sacc[kt] = mfma16(ah, bl, sacc[kt]);
                sacc[kt] = mfma16(al, bh, sacc[kt]);
            }
        }
        {
            const int qc = w * 16 + lq;
            #pragma unroll
            for (int kt = 0; kt < 2; ++kt) {
                s16x4 ph, pl;
                #pragma unroll
                for (int r = 0; r < 4; ++r) {
                    int kg = k0 + kt * 16 + g * 4 + r;
                    float p = __expf(sacc[kt][r] - mB[kg]) * ilB[kg];
                    short h, l; split_bf16(p, h, l);
                    ph[r] = h; pl[r] = l;
                }
                *(s16x4*)&PtH[qc][kt * 16 + g * 4] = ph;
                *(s16x4*)&PtL[qc][kt * 16 + g * 4] = pl;
            }
        }
        __syncthreads();
        #pragma unroll
        for (int kc = 0; kc < 2; ++kc) {
            bf16x8 pbh[2], pbl[2];
            #pragma unroll
            for (int qt = 0; qt < 2; ++qt) {
                pbh[qt] = *(const bf16x8*)&PtH[qt * 32 + l32][kc * 16 + g2 * 8];
                pbl[qt] = *(const bf16x8*)&PtL[qt * 32 + l32][kc * 16 + g2 * 8];
            }
            #pragma unroll
            for (int mt = 0; mt < 2; ++mt) {
                const int v = w * 64 + mt * 32 + l32;
                const float* vp = Vb + (size_t)v * HW + k0 + kc * 16 + g2 * 8;
                f32x4 x0 = *(const f32x4*)vp;
                f32x4 x1 = *(const f32x4*)(vp + 4);
                bf16x8 ah, al;
                #pragma unroll
                for (int j = 0; j < 4; ++j) {
                    short h, l;
                    split_bf16(x0[j], h, l); ah[j] = h;     al[j] = l;
                    split_bf16(x1[j], h, l); ah[4 + j] = h; al[4 + j] = l;
                }
                #pragma unroll
                for (int qt = 0; qt < 2; ++qt) {
                    acc[mt][qt] = mfma32(ah, pbh[qt], acc[mt][qt]);
                    acc[mt][qt] = mfma32(ah, pbl[qt], acc[mt][qt]);
                    acc[mt][qt] = mfma32(al, pbh[qt], acc[mt][qt]);
                }
            }
        }
    }
    float* ob = out + (size_t)b * DIM * HW;
    #pragma unroll
    for (int mt = 0; mt < 2; ++mt)
        #pragma unroll
        for (int qt = 0; qt < 2; ++qt)
            #pragma unroll
            for (int r = 0; r < 16; ++r) {
                int v = w * 64 + mt * 32 + (r & 3) + 8 * (r >> 2) + 4 * g2;
                int q = q0 + qt * 32 + l32;
                ob[(size_t)v * HW + q] = acc[mt][qt][r];
            }
}

// ===========================================================================
extern "C" void kernel_launch(void* const* d_in, const int* in_sizes, int n_in,
                              void* d_out, int out_size, void* d_ws, size_t ws_size,
                              hipStream_t stream)
{
    (void)in_sizes; (void)n_in; (void)out_size;
    const float* K = (const float*)d_in[0];
    const float* Q = (const float*)d_in[1];
    const float* V = (const float*)d_in[2];

    char* wsb = (char*)d_ws;
    float* m_ws  = (float*)wsb;
    float* il_ws = m_ws + (size_t)NB * HW;

    const size_t planeElems = (size_t)NB * HW * DIM;   // shorts per plane
    const size_t statsBytes = 262144;
    const size_t need = statsBytes + planeElems * 2 * 4 /*KTh,KTl,QTh,QTl*/
                                   + planeElems * 2 * 2 /*V2*/;

    dim3 blk(256);
    if (ws_size >= need) {
        short* KTh = (short*)(wsb + statsBytes);
        short* KTl = KTh + planeElems;
        short* QTh = KTl + planeElems;
        short* QTl = QTh + planeElems;
        short* V2  = QTl + planeElems;

        dim3 gT(HW / 16, NB);     // 256 x 8
        pass0_T<<<gT, blk, 0, stream>>>(K, KTh, KTl);
        pass0_T<<<gT, blk, 0, stream>>>(Q, QTh, QTl);
        dim3 gV(DIM, NB);         // 256 x 8
        pass0_V<<<gV, blk, 0, stream>>>(V, V2);

        dim3 blk5(512);
        k9_stats<<<dim3(256), blk5, 0, stream>>>(KTh, KTl, QTh, QTl, m_ws, il_ws);
        k10_out<<<dim3(512), blk5, 0, stream>>>(KTh, KTl, QTh, QTl, V2,
                                                m_ws, il_ws, (float*)d_out);
    } else {
        dim3 gM(64, NB);
        k_stats<<<gM, blk, 0, stream>>>(K, Q, m_ws, il_ws);
        k_attn_out<<<gM, blk, 0, stream>>>(K, Q, V, m_ws, il_ws, (float*)d_out);
    }
}

// Round 11
// 651.149 us; speedup vs baseline: 1.9447x; 1.9447x over previous
//
#include <hip/hip_runtime.h>

#define HW   4096
#define DIM  256
#define NB   8

typedef short bf16x8 __attribute__((ext_vector_type(8)));
typedef short s16x4  __attribute__((ext_vector_type(4)));
typedef float f32x4  __attribute__((ext_vector_type(4)));
typedef float f32x16 __attribute__((ext_vector_type(16)));
typedef unsigned int u32_g __attribute__((address_space(1)));
typedef unsigned int u32_l __attribute__((address_space(3)));

// round-to-nearest-even split of fp32 into bf16 hi + bf16 lo
__device__ __forceinline__ void split_bf16(float x, short& hi, short& lo) {
    unsigned u  = __builtin_bit_cast(unsigned, x);
    unsigned rh = (u + 0x7FFFu + ((u >> 16) & 1u)) >> 16;
    hi = (short)rh;
    float hf  = __builtin_bit_cast(float, rh << 16);
    float rem = x - hf;
    unsigned u2 = __builtin_bit_cast(unsigned, rem);
    unsigned rl = (u2 + 0x7FFFu + ((u2 >> 16) & 1u)) >> 16;
    lo = (short)rl;
}

__device__ __forceinline__ f32x4 mfma16(bf16x8 a, bf16x8 b, f32x4 c) {
    return __builtin_amdgcn_mfma_f32_16x16x32_bf16(a, b, c, 0, 0, 0);
}
__device__ __forceinline__ f32x16 mfma32(bf16x8 a, bf16x8 b, f32x16 c) {
    return __builtin_amdgcn_mfma_f32_32x32x16_bf16(a, b, c, 0, 0, 0);
}

__device__ __forceinline__ void gload16(const void* g, void* l) {
    __builtin_amdgcn_global_load_lds((const u32_g*)g, (u32_l*)l, 16, 0, 0);
}
__device__ __forceinline__ void gload4(const void* g, void* l) {
    __builtin_amdgcn_global_load_lds((const u32_g*)g, (u32_l*)l, 4, 0, 0);
}

// ===========================================================================
// pass0_T: X[b][256][4096] f32 -> XT_hi/lo[b][4096][256] bf16-shorts,
// each 512-B output row byte-swizzled: colbyte ^= ((row&15)<<4)
// ===========================================================================
extern "C" __global__ void __launch_bounds__(256)
pass0_T(const float* __restrict__ src, short* __restrict__ dsth,
        short* __restrict__ dstl)
{
    __shared__ __attribute__((aligned(16))) short TH[16][264];
    __shared__ __attribute__((aligned(16))) short TL[16][264];
    const int b   = blockIdx.y;
    const int hw0 = blockIdx.x * 16;
    const int t   = threadIdx.x;
    const float* sb = src + (size_t)b * DIM * HW;

    {
        const int rl = t & 15;     // hw within tile
        const int dl = t >> 4;     // d base
        #pragma unroll
        for (int dp = 0; dp < 16; ++dp) {
            int d = dl + dp * 16;
            float x = sb[(size_t)d * HW + hw0 + rl];
            short h, l; split_bf16(x, h, l);
            TH[rl][d] = h; TL[rl][d] = l;
        }
    }
    __syncthreads();

    const int r   = t >> 4;          // row (hw) in tile, 0..15
    const int c0  = (t & 15) * 2;    // first 16-B chunk of 2
    const int swz = r << 4;          // (hw0+r)&15 == r
    size_t rowbyte = ((size_t)b * HW + hw0 + r) * (size_t)(DIM * 2);
    char* dh = (char*)dsth + rowbyte;
    char* dl = (char*)dstl + rowbyte;
    #pragma unroll
    for (int j = 0; j < 2; ++j) {
        int cb  = (c0 + j) * 16;
        int cbs = cb ^ swz;
        *(f32x4*)(dh + cbs) = *(const f32x4*)((const char*)&TH[r][0] + cb);
        *(f32x4*)(dl + cbs) = *(const f32x4*)((const char*)&TL[r][0] + cb);
    }
}

// pass0_V: V[b][256][4096] f32 -> V2[b][512 segs][256 v][8 hi + 8 lo] shorts
extern "C" __global__ void __launch_bounds__(256)
pass0_V(const float* __restrict__ V, short* __restrict__ v2)
{
    const int b = blockIdx.y, v = blockIdx.x, t = threadIdx.x;
    const float* sv = V + ((size_t)b * DIM + v) * HW + t * 16;
    #pragma unroll
    for (int s = 0; s < 2; ++s) {
        f32x4 x0 = *(const f32x4*)(sv + s * 8);
        f32x4 x1 = *(const f32x4*)(sv + s * 8 + 4);
        s16x4 h0, l0, h1, l1;
        #pragma unroll
        for (int j = 0; j < 4; ++j) {
            short h, l;
            split_bf16(x0[j], h, l); h0[j] = h; l0[j] = l;
            split_bf16(x1[j], h, l); h1[j] = h; l1[j] = l;
        }
        short* dp = v2 + (((size_t)b * 512 + (size_t)(t * 2 + s)) * DIM + v) * 16;
        *(s16x4*)(dp + 0)  = h0;
        *(s16x4*)(dp + 4)  = h1;
        *(s16x4*)(dp + 8)  = l0;
        *(s16x4*)(dp + 12) = l1;
    }
}

// ===========================================================================
// k9_stats (unchanged, proven): per-k-column online max / exp-sum over all q.
// ===========================================================================
extern "C" __global__ void __launch_bounds__(512, 2)
k9_stats(const short* __restrict__ KTh, const short* __restrict__ KTl,
         const short* __restrict__ QTh, const short* __restrict__ QTl,
         float* __restrict__ m_out, float* __restrict__ il_out)
{
    __shared__ __attribute__((aligned(16))) short QH[2][64][256];  // 64 KB
    __shared__ __attribute__((aligned(16))) short QL[2][64][256];  // 64 KB
    __shared__ __attribute__((aligned(16))) float MRG[2][128][2];  // 2 KB

    const int id   = blockIdx.x;
    const int b    = id & 7;
    const int k0b  = (id >> 3) * 128;
    const int t    = threadIdx.x;
    const int lane = t & 63;
    const int w    = t >> 6;
    const int l32  = lane & 31;
    const int g2   = lane >> 5;
    const int wk   = w >> 1;        // k quarter (32 rows)
    const int wq   = w & 1;         // q half (32 cols)

    bf16x8 kh[16], kl[16];
    {
        const int krow = k0b + wk * 32 + l32;
        const char* rh = (const char*)KTh + ((size_t)b * HW + krow) * 512;
        const char* rl = (const char*)KTl + ((size_t)b * HW + krow) * 512;
        const int swz = (l32 & 15) << 4;
        #pragma unroll
        for (int s = 0; s < 16; ++s) {
            int cb = (s * 32 + g2 * 16) ^ swz;
            kh[s] = *(const bf16x8*)(rh + cb);
            kl[s] = *(const bf16x8*)(rl + cb);
        }
    }

    const char* qhbase = (const char*)QTh + (size_t)b * HW * 512;
    const char* qlbase = (const char*)QTl + (size_t)b * HW * 512;
    auto stage = [&](int bi, int q0s) {
        #pragma unroll
        for (int j = 0; j < 4; ++j) {
            int cc = (j << 3) + w;             // 0..31 chunks of 1 KB
            int o  = cc * 1024;
            gload16(qhbase + (size_t)q0s * 512 + o + lane * 16,
                    (char*)&QH[bi][0][0] + o);
            gload16(qlbase + (size_t)q0s * 512 + o + lane * 16,
                    (char*)&QL[bi][0][0] + o);
        }
    };

    const int qrow = wq * 32 + l32;
    const int qswz = (l32 & 15) << 4;   // qrow&15 == l32&15

    float mr[16], lr[16];
    #pragma unroll
    for (int r = 0; r < 16; ++r) { mr[r] = -3.0e38f; lr[r] = 0.0f; }

    stage(0, 0);
    __syncthreads();

    for (int it = 0; it < 64; ++it) {
        const int cur = it & 1;
        if (it + 1 < 64) stage(cur ^ 1, (it + 1) * 64);

        const char* bhr = (const char*)&QH[cur][qrow][0];
        const char* blr = (const char*)&QL[cur][qrow][0];
        f32x16 cS;
        #pragma unroll
        for (int e = 0; e < 16; ++e) cS[e] = 0.0f;

        __builtin_amdgcn_s_setprio(1);
        #pragma unroll
        for (int s = 0; s < 16; ++s) {
            int cb = (s * 32 + g2 * 16) ^ qswz;
            bf16x8 bh = *(const bf16x8*)(bhr + cb);
            bf16x8 bl = *(const bf16x8*)(blr + cb);
            cS = mfma32(kh[s], bh, cS);         // Kh*Qh
            cS = mfma32(kh[s], bl, cS);         // Kh*Ql
            cS = mfma32(kl[s], bh, cS);         // Kl*Qh
        }
        __builtin_amdgcn_s_setprio(0);

        #pragma unroll
        for (int r = 0; r < 16; ++r) {
            float sv = cS[r];
            float nm = fmaxf(mr[r], sv);
            lr[r] = lr[r] * __expf(mr[r] - nm) + __expf(sv - nm);
            mr[r] = nm;
        }
        __syncthreads();
    }

    #pragma unroll
    for (int r = 0; r < 16; ++r) {
        float m = mr[r], l = lr[r];
        #pragma unroll
        for (int off = 1; off < 32; off <<= 1) {
            float m2 = __shfl_xor(m, off);
            float l2 = __shfl_xor(l, off);
            float nm = fmaxf(m, m2);
            l = l * __expf(m - nm) + l2 * __expf(m2 - nm);
            m = nm;
        }
        mr[r] = m; lr[r] = l;
    }
    if (l32 == 0) {
        #pragma unroll
        for (int r = 0; r < 16; ++r) {
            int klo = wk * 32 + 4 * g2 + (r & 3) + 8 * (r >> 2);
            MRG[wq][klo][0] = mr[r];
            MRG[wq][klo][1] = lr[r];
        }
    }
    __syncthreads();
    if (t < 128) {
        float m0 = MRG[0][t][0], l0 = MRG[0][t][1];
        float m1 = MRG[1][t][0], l1 = MRG[1][t][1];
        float nm = fmaxf(m0, m1);
        float l  = l0 * __expf(m0 - nm) + l1 * __expf(m1 - nm);
        m_out[b * HW + k0b + t]  = nm;
        il_out[b * HW + k0b + t] = 1.0f / l;
    }
}

// ===========================================================================
// k11_out: k3's schedule (BQ=128, BK=32, 2 barriers, mfma16 S^T, 128 iters)
// with k9's data plumbing: pre-split swizzled planes staged via gload16 DMA
// (K-hi & K-lo dbuf [2][32][256] each), Q-frags register-resident, P[128][68]
// (proven conflict-free), MI dbuf broadcast, V via pre-split V2 + kc0
// prefetch. LDS 99 KB. grid 256 blocks, id&7 = batch (XCD-aligned).
// ===========================================================================
extern "C" __global__ void __launch_bounds__(512, 2)
k11_out(const short* __restrict__ KTh, const short* __restrict__ KTl,
        const short* __restrict__ QTh, const short* __restrict__ QTl,
        const short* __restrict__ V2,
        const float* __restrict__ m_in, const float* __restrict__ il_in,
        float* __restrict__ out)
{
    __shared__ __attribute__((aligned(16))) short KH[2][32][256];  // 32 KB
    __shared__ __attribute__((aligned(16))) short KL[2][32][256];  // 32 KB
    __shared__ __attribute__((aligned(16))) short PH[128][68];     // 17 KB
    __shared__ __attribute__((aligned(16))) short PL[128][68];     // 17 KB
    __shared__ __attribute__((aligned(16))) float MI[2][128];      // 1 KB

    const int id   = blockIdx.x;
    const int b    = id & 7;
    const int q0   = (id >> 3) * 128;
    const int t    = threadIdx.x;
    const int lane = t & 63;
    const int w    = t >> 6;
    const int lq   = lane & 15;
    const int g    = lane >> 4;     // 0..3
    const int l32  = lane & 31;
    const int g2   = lane >> 5;
    const int wv   = w >> 1;        // PV v-quarter
    const int wq2  = w & 1;         // PV q-half

    // Q fragments (hi+lo) register-resident: row q0 + w*16 + lq
    bf16x8 qh[8], ql[8];
    {
        const int qrow = q0 + w * 16 + lq;
        const char* rh = (const char*)QTh + ((size_t)b * HW + qrow) * 512;
        const char* rl = (const char*)QTl + ((size_t)b * HW + qrow) * 512;
        const int swz = lq << 4;    // qrow&15 == lq
        #pragma unroll
        for (int ds = 0; ds < 8; ++ds) {
            int cb = (64 * ds + 16 * g) ^ swz;
            qh[ds] = *(const bf16x8*)(rh + cb);
            ql[ds] = *(const bf16x8*)(rl + cb);
        }
    }

    const char* khbase = (const char*)KTh + (size_t)b * HW * 512;
    const char* klbase = (const char*)KTl + (size_t)b * HW * 512;
    auto stageK = [&](int bi, int k0s) {
        #pragma unroll
        for (int j = 0; j < 2; ++j) {
            int cc = (j << 3) + w;             // 0..15 chunks of 1 KB
            int o  = cc * 1024;
            gload16(khbase + (size_t)k0s * 512 + o + lane * 16,
                    (char*)&KH[bi][0][0] + o);
            gload16(klbase + (size_t)k0s * 512 + o + lane * 16,
                    (char*)&KL[bi][0][0] + o);
        }
    };
    const float* mB  = m_in  + b * HW;
    const float* ilB = il_in + b * HW;
    auto stageMI = [&](int bi, int k0s) {
        if (w == 0) {
            // lanes 0..63 load 64 floats; only first 32 are used (BK=32).
            gload4(mB  + k0s + lane, (char*)&MI[bi][0]);
            gload4(ilB + k0s + lane, (char*)&MI[bi][64]);
        }
    };

    f32x16 acc[2][2];
    #pragma unroll
    for (int i = 0; i < 2; ++i)
        #pragma unroll
        for (int j = 0; j < 2; ++j)
            #pragma unroll
            for (int e = 0; e < 16; ++e) acc[i][j][e] = 0.0f;

    stageK(0, 0);
    stageMI(0, 0);
    __syncthreads();

    const int swzk = lq << 4;       // (kt*16+lq)&15 == lq
    const int prow = w * 16 + lq;

    for (int it = 0; it < 128; ++it) {
        const int cur = it & 1;
        const int k0  = it * 32;

        // top-of-iter: next K tiles + MI -> LDS DMA (drained at bar1, hidden
        // under S^T); kc0 V fragments -> regs
        if (it + 1 < 128) {
            stageK(cur ^ 1, k0 + 32);
            stageMI(cur ^ 1, k0 + 32);
        }
        bf16x8 v0h[2], v0l[2];
        {
            const int seg = it * 4 + g2;       // kc = 0
            #pragma unroll
            for (int mt = 0; mt < 2; ++mt) {
                int v = wv * 64 + mt * 32 + l32;
                const short* vp = V2 + (((size_t)b * 512 + seg) * DIM + v) * 16;
                v0h[mt] = *(const bf16x8*)(vp);
                v0l[mt] = *(const bf16x8*)(vp + 8);
            }
        }

        // ---- S^T: mfma16, k3's chain order (3 per (ds,kt)) ----
        const char* ahr0 = (const char*)&KH[cur][lq][0];
        const char* ahr1 = (const char*)&KH[cur][16 + lq][0];
        const char* alr0 = (const char*)&KL[cur][lq][0];
        const char* alr1 = (const char*)&KL[cur][16 + lq][0];
        f32x4 sacc[2];
        #pragma unroll
        for (int kt = 0; kt < 2; ++kt) { f32x4 z = {0.f,0.f,0.f,0.f}; sacc[kt] = z; }

        __builtin_amdgcn_s_setprio(1);
        #pragma unroll
        for (int ds = 0; ds < 8; ++ds) {
            int cb = (64 * ds + 16 * g) ^ swzk;
            bf16x8 bh = qh[ds];
            bf16x8 bl = ql[ds];
            {
                bf16x8 ah = *(const bf16x8*)(ahr0 + cb);
                bf16x8 al = *(const bf16x8*)(alr0 + cb);
                sacc[0] = mfma16(ah, bh, sacc[0]);
                sacc[0] = mfma16(ah, bl, sacc[0]);
                sacc[0] = mfma16(al, bh, sacc[0]);
            }
            {
                bf16x8 ah = *(const bf16x8*)(ahr1 + cb);
                bf16x8 al = *(const bf16x8*)(alr1 + cb);
                sacc[1] = mfma16(ah, bh, sacc[1]);
                sacc[1] = mfma16(ah, bl, sacc[1]);
                sacc[1] = mfma16(al, bh, sacc[1]);
            }
        }
        __builtin_amdgcn_s_setprio(0);

        __syncthreads();   // bar1: staging drained; PV(it-1) P-reads done

        // ---- exp + split-bf16 + P write (MI broadcast) ----
        #pragma unroll
        for (int kt = 0; kt < 2; ++kt) {
            int idx = kt * 16 + g * 4;
            f32x4 m4 = *(const f32x4*)&MI[cur][idx];
            f32x4 i4 = *(const f32x4*)&MI[cur][64 + idx];
            s16x4 ph, pl;
            #pragma unroll
            for (int r = 0; r < 4; ++r) {
                float p = __expf(sacc[kt][r] - m4[r]) * i4[r];
                short h, l; split_bf16(p, h, l);
                ph[r] = h; pl[r] = l;
            }
            *(s16x4*)&PH[prow][idx] = ph;
            *(s16x4*)&PL[prow][idx] = pl;
        }

        __syncthreads();   // bar2: P visible

        // ---- PV: D[v][q] += V[v][k] * P[k][q], 2 x 16-k steps ----
        __builtin_amdgcn_s_setprio(1);
        #pragma unroll
        for (int kc = 0; kc < 2; ++kc) {
            bf16x8 pbh[2], pbl[2];
            #pragma unroll
            for (int qt = 0; qt < 2; ++qt) {
                int pr = wq2 * 64 + qt * 32 + l32;
                const short* p0 = &PH[pr][kc * 16 + g2 * 8];
                const short* p1 = &PL[pr][kc * 16 + g2 * 8];
                s16x4 a0 = *(const s16x4*)(p0);
                s16x4 a1 = *(const s16x4*)(p0 + 4);
                s16x4 b0 = *(const s16x4*)(p1);
                s16x4 b1 = *(const s16x4*)(p1 + 4);
                pbh[qt] = __builtin_shufflevector(a0, a1, 0, 1, 2, 3, 4, 5, 6, 7);
                pbl[qt] = __builtin_shufflevector(b0, b1, 0, 1, 2, 3, 4, 5, 6, 7);
            }
            const int seg = it * 4 + kc * 2 + g2;
            #pragma unroll
            for (int mt = 0; mt < 2; ++mt) {
                bf16x8 vh, vl;
                if (kc == 0) {
                    vh = v0h[mt]; vl = v0l[mt];
                } else {
                    int v = wv * 64 + mt * 32 + l32;
                    const short* vp = V2 + (((size_t)b * 512 + seg) * DIM + v) * 16;
                    vh = *(const bf16x8*)(vp);
                    vl = *(const bf16x8*)(vp + 8);
                }
                #pragma unroll
                for (int qt = 0; qt < 2; ++qt) {
                    acc[mt][qt] = mfma32(vh, pbh[qt], acc[mt][qt]);
                    acc[mt][qt] = mfma32(vh, pbl[qt], acc[mt][qt]);
                    acc[mt][qt] = mfma32(vl, pbh[qt], acc[mt][qt]);
                }
            }
        }
        __builtin_amdgcn_s_setprio(0);
    }

    // epilogue: col q = wq2*64 + qt*32 + l32; row v = wv*64 + mt*32 +
    // (r&3)+8*(r>>2)+4*g2
    float* __restrict__ ob = out + (size_t)b * DIM * HW;
    #pragma unroll
    for (int mt = 0; mt < 2; ++mt)
        #pragma unroll
        for (int qt = 0; qt < 2; ++qt)
            #pragma unroll
            for (int r = 0; r < 16; ++r) {
                int v = wv * 64 + mt * 32 + (r & 3) + 8 * (r >> 2) + 4 * g2;
                int q = q0 + wq2 * 64 + qt * 32 + l32;
                ob[(size_t)v * HW + q] = acc[mt][qt][r];
            }
}

// ===========================================================================
// FALLBACK PATH (round-1 passing kernels, used only if ws too small)
// ===========================================================================
extern "C" __global__ void __launch_bounds__(256, 1)
k_stats(const float* __restrict__ K, const float* __restrict__ Q,
        float* __restrict__ m_out, float* __restrict__ il_out)
{
    __shared__ __attribute__((aligned(16))) short KtH[64][264];
    __shared__ __attribute__((aligned(16))) short KtL[64][264];
    __shared__ __attribute__((aligned(16))) short QtH[32][264];
    __shared__ __attribute__((aligned(16))) short QtL[32][264];

    const int b = blockIdx.y, k0 = blockIdx.x * 64, t = threadIdx.x;
    const int lane = t & 63, w = t >> 6, g = lane >> 4, lq = lane & 15;
    const float* Kb = K + (size_t)b * DIM * HW;
    const float* Qb = Q + (size_t)b * DIM * HW;

    {
        const int kk = t & 63, d0 = t >> 6;
        #pragma unroll 4
        for (int pass = 0; pass < 64; ++pass) {
            int d = d0 + pass * 4;
            float x = Kb[(size_t)d * HW + k0 + kk];
            short h, l; split_bf16(x, h, l);
            KtH[kk][d] = h; KtL[kk][d] = l;
        }
    }
    float mr[4], lr[4];
    #pragma unroll
    for (int r = 0; r < 4; ++r) { mr[r] = -3.0e38f; lr[r] = 0.0f; }

    for (int q0 = 0; q0 < HW; q0 += 32) {
        __syncthreads();
        {
            const int qq = t & 31, d0 = t >> 5;
            #pragma unroll 4
            for (int pass = 0; pass < 32; ++pass) {
                int d = d0 + pass * 8;
                float x = Qb[(size_t)d * HW + q0 + qq];
                short h, l; split_bf16(x, h, l);
                QtH[qq][d] = h; QtL[qq][d] = l;
            }
        }
        __syncthreads();
        #pragma unroll
        for (int qt = 0; qt < 2; ++qt) {
            f32x4 acc = {0.f, 0.f, 0.f, 0.f};
            #pragma unroll
            for (int ds = 0; ds < 8; ++ds) {
                const int dof = ds * 32 + g * 8;
                bf16x8 ah = *(const bf16x8*)&KtH[w * 16 + lq][dof];
                bf16x8 al = *(const bf16x8*)&KtL[w * 16 + lq][dof];
                bf16x8 bh = *(const bf16x8*)&QtH[qt * 16 + lq][dof];
                bf16x8 bl = *(const bf16x8*)&QtL[qt * 16 + lq][dof];
                acc = mfma16(ah, bh, acc);
                acc = mfma16(ah, bl, acc);
                acc = mfma16(al, bh, acc);
            }
            #pragma unroll
            for (int r = 0; r < 4; ++r) {
                float s = acc[r];
                if (s > mr[r]) { lr[r] = lr[r] * __expf(mr[r] - s) + 1.0f; mr[r] = s; }
                else lr[r] += __expf(s - mr[r]);
            }
        }
    }
    #pragma unroll
    for (int r = 0; r < 4; ++r) {
        float m = mr[r], l = lr[r];
        #pragma unroll
        for (int off = 1; off < 16; off <<= 1) {
            float m2 = __shfl_xor(m, off), l2 = __shfl_xor(l, off);
            float mn = fmaxf(m, m2);
            l = l * __expf(m - mn) + l2 * __expf(m2 - mn);
            m = mn;
        }
        if (lq == 0) {
            int kg = k0 + w * 16 + g * 4 + r;
            m_out[b * HW + kg] = m;
            il_out[b * HW + kg] = 1.0f / l;
        }
    }
}

extern "C" __global__ void __launch_bounds__(256, 1)
k_attn_out(const float* __restrict__ K, const float* __restrict__ Q,
           const float* __restrict__ V,
           const float* __restrict__ m_in, const float* __restrict__ il_in,
           float* __restrict__ out)
{
    __shared__ __attribute__((aligned(16))) short QtH[64][264];
    __shared__ __attribute__((aligned(16))) short QtL[64][264];
    __shared__ __attribute__((aligned(16))) short KtH[32][264];
    __shared__ __attribute__((aligned(16))) short KtL[32][264];
    __shared__ __attribute__((aligned(16))) short PtH[64][40];
    __shared__ __attribute__((aligned(16))) short PtL[64][40];

    const int b = blockIdx.y, q0 = blockIdx.x * 64, t = threadIdx.x;
    const int lane = t & 63, w = t >> 6, g = lane >> 4, lq = lane & 15;
    const int g2 = lane >> 5, l32 = lane & 31;
    const float* Kb = K + (size_t)b * DIM * HW;
    const float* Qb = Q + (size_t)b * DIM * HW;
    const float* Vb = V + (size_t)b * DIM * HW;
    const float* mB = m_in + b * HW;
    const float* ilB = il_in + b * HW;

    {
        const int qq = t & 63, d0 = t >> 6;
        #pragma unroll 4
        for (int pass = 0; pass < 64; ++pass) {
            int d = d0 + pass * 4;
            float x = Qb[(size_t)d * HW + q0 + qq];
            short h, l; split_bf16(x, h, l);
            QtH[qq][d] = h; QtL[qq][d] = l;
        }
    }
    f32x16 acc[2][2];
    #pragma unroll
    for (int i = 0; i < 2; ++i)
        #pragma unroll
        for (int j = 0; j < 2; ++j)
            #pragma unroll
            for (int e = 0; e < 16; ++e) acc[i][j][e] = 0.0f;

    for (int k0 = 0; k0 < HW; k0 += 32) {
        __syncthreads();
        {
            const int kk = t & 31, d0 = t >> 5;
            #pragma unroll 4
            for (int pass = 0; pass < 32; ++pass) {
                int d = d0 + pass * 8;
                float x = Kb[(size_t)d * HW + k0 + kk];
                short h, l; split_bf16(x, h, l);
                KtH[kk][d] = h; KtL[kk][d] = l;
            }
        }
        __syncthreads();
        f32x4 sacc[2];
        #pragma unroll
        for (int kt = 0; kt < 2; ++kt) { f32x4 z = {0.f,0.f,0.f,0.f}; sacc[kt] = z; }
        #pragma unroll
        for (int ds = 0; ds < 8; ++ds) {
            const int dof = ds * 32 + g * 8;
            bf16x8 bh = *(const bf16x8*)&QtH[w * 16 + lq][dof];
            bf16x8 bl = *(const bf16x8*)&QtL[w * 16 + lq][dof];
            #pragma unroll
            for (int kt = 0; kt < 2; ++kt) {
                bf16x8 ah = *(const bf16x8*)&KtH[kt * 16 + lq][dof];
                bf16x8 al = *(const bf16x8*)&KtL[kt * 16 + lq][dof];
                sacc[kt] = mfma16(ah, bh, sacc[kt]);
                sacc[kt] = mfma16(ah, bl, sacc[kt]);
                sacc[kt] = mfma16(al, bh, sacc[kt]);
            }
        }
        {
            const int qc = w * 16 + lq;
            #pragma unroll
            for (int kt = 0; kt < 2; ++kt) {
                s16x4 ph, pl;
                #pragma unroll
                for (int r = 0; r < 4; ++r) {
                    int kg = k0 + kt * 16 + g * 4 + r;
                    float p = __expf(sacc[kt][r] - mB[kg]) * ilB[kg];
                    short h, l; split_bf16(p, h, l);
                    ph[r] = h; pl[r] = l;
                }
                *(s16x4*)&PtH[qc][kt * 16 + g * 4] = ph;
                *(s16x4*)&PtL[qc][kt * 16 + g * 4] = pl;
            }
        }
        __syncthreads();
        #pragma unroll
        for (int kc = 0; kc < 2; ++kc) {
            bf16x8 pbh[2], pbl[2];
            #pragma unroll
            for (int qt = 0; qt < 2; ++qt) {
                pbh[qt] = *(const bf16x8*)&PtH[qt * 32 + l32][kc * 16 + g2 * 8];
                pbl[qt] = *(const bf16x8*)&PtL[qt * 32 + l32][kc * 16 + g2 * 8];
            }
            #pragma unroll
            for (int mt = 0; mt < 2; ++mt) {
                const int v = w * 64 + mt * 32 + l32;
                const float* vp = Vb + (size_t)v * HW + k0 + kc * 16 + g2 * 8;
                f32x4 x0 = *(const f32x4*)vp;
                f32x4 x1 = *(const f32x4*)(vp + 4);
                bf16x8 ah, al;
                #pragma unroll
                for (int j = 0; j < 4; ++j) {
                    short h, l;
                    split_bf16(x0[j], h, l); ah[j] = h;     al[j] = l;
                    split_bf16(x1[j], h, l); ah[4 + j] = h; al[4 + j] = l;
                }
                #pragma unroll
                for (int qt = 0; qt < 2; ++qt) {
                    acc[mt][qt] = mfma32(ah, pbh[qt], acc[mt][qt]);
                    acc[mt][qt] = mfma32(ah, pbl[qt], acc[mt][qt]);
                    acc[mt][qt] = mfma32(al, pbh[qt], acc[mt][qt]);
                }
            }
        }
    }
    float* ob = out + (size_t)b * DIM * HW;
    #pragma unroll
    for (int mt = 0; mt < 2; ++mt)
        #pragma unroll
        for (int qt = 0; qt < 2; ++qt)
            #pragma unroll
            for (int r = 0; r < 16; ++r) {
                int v = w * 64 + mt * 32 + (r & 3) + 8 * (r >> 2) + 4 * g2;
                int q = q0 + qt * 32 + l32;
                ob[(size_t)v * HW + q] = acc[mt][qt][r];
            }
}

// ===========================================================================
extern "C" void kernel_launch(void* const* d_in, const int* in_sizes, int n_in,
                              void* d_out, int out_size, void* d_ws, size_t ws_size,
                              hipStream_t stream)
{
    (void)in_sizes; (void)n_in; (void)out_size;
    const float* K = (const float*)d_in[0];
    const float* Q = (const float*)d_in[1];
    const float* V = (const float*)d_in[2];

    char* wsb = (char*)d_ws;
    float* m_ws  = (float*)wsb;
    float* il_ws = m_ws + (size_t)NB * HW;

    const size_t planeElems = (size_t)NB * HW * DIM;   // shorts per plane
    const size_t statsBytes = 262144;
    const size_t need = statsBytes + planeElems * 2 * 4 /*KTh,KTl,QTh,QTl*/
                                   + planeElems * 2 * 2 /*V2*/;

    dim3 blk(256);
    if (ws_size >= need) {
        short* KTh = (short*)(wsb + statsBytes);
        short* KTl = KTh + planeElems;
        short* QTh = KTl + planeElems;
        short* QTl = QTh + planeElems;
        short* V2  = QTl + planeElems;

        dim3 gT(HW / 16, NB);     // 256 x 8
        pass0_T<<<gT, blk, 0, stream>>>(K, KTh, KTl);
        pass0_T<<<gT, blk, 0, stream>>>(Q, QTh, QTl);
        dim3 gV(DIM, NB);         // 256 x 8
        pass0_V<<<gV, blk, 0, stream>>>(V, V2);

        dim3 blk5(512);
        k9_stats<<<dim3(256), blk5, 0, stream>>>(KTh, KTl, QTh, QTl, m_ws, il_ws);
        k11_out<<<dim3(256), blk5, 0, stream>>>(KTh, KTl, QTh, QTl, V2,
                                                m_ws, il_ws, (float*)d_out);
    } else {
        dim3 gM(64, NB);
        k_stats<<<gM, blk, 0, stream>>>(K, Q, m_ws, il_ws);
        k_attn_out<<<gM, blk, 0, stream>>>(K, Q, V, m_ws, il_ws, (float*)d_out);
    }
}